// Round 3
// baseline (209.384 us; speedup 1.0000x reference)
//
#include <hip/hip_runtime.h>
#include <hip/hip_bf16.h>
#include <math.h>

#define B_ 2
#define H_ 12
#define S_ 1024
#define D_ 128
#define TQ 32
#define TK 32
#define NW 4
#define SCALE 0.08838834764831843f

#define QROWS (S_ + 16)            /* 1040 */
#define KROWS (16 + S_ + 16)       /* 1056 */

#define QBLK 3120                  /* 24*1040*128/4/256 */
#define KBLK 3168                  /* 24*1056*128/4/256 */
#define VBLK 3072                  /* 24*32*4 transpose tiles */

typedef __attribute__((ext_vector_type(8))) short short8;
typedef __attribute__((ext_vector_type(4))) float floatx4;

__device__ __forceinline__ unsigned short f2b(float f) {
    return __builtin_bit_cast(unsigned short, __float2bfloat16(f));
}

// ---- fused prepass: Q/K f32->bf16 padded, V -> V^T bf16 --------------------
__global__ __launch_bounds__(256) void prep_kernel(
    const float* __restrict__ Q, const float* __restrict__ K,
    const float* __restrict__ V,
    unsigned short* __restrict__ Qp, unsigned short* __restrict__ Kp,
    unsigned short* __restrict__ Vt)
{
    __shared__ float ls[32][33];
    const int bid = blockIdx.x;
    const int tid = threadIdx.x;
    if (bid < QBLK) {
        int e0 = (bid * 256 + tid) * 4;          // < 3.2M, fits int
        int bh = e0 / (QROWS * D_);              // magic-mul (const divisor)
        int rem = e0 - bh * (QROWS * D_);
        int r = rem >> 7, d = rem & 127;
        int sr = r - 16;
        float4 v = make_float4(0.f, 0.f, 0.f, 0.f);
        if (sr >= 0 && sr < S_) v = *(const float4*)(Q + ((size_t)bh * S_ + sr) * D_ + d);
        ushort4 o; o.x = f2b(v.x); o.y = f2b(v.y); o.z = f2b(v.z); o.w = f2b(v.w);
        *(ushort4*)(Qp + ((size_t)bh * QROWS + r) * D_ + d) = o;
    } else if (bid < QBLK + KBLK) {
        int e0 = ((bid - QBLK) * 256 + tid) * 4;
        int bh = e0 / (KROWS * D_);
        int rem = e0 - bh * (KROWS * D_);
        int r = rem >> 7, d = rem & 127;
        int sr = r - 16;
        float4 v = make_float4(0.f, 0.f, 0.f, 0.f);
        if (sr >= 0 && sr < S_) v = *(const float4*)(K + ((size_t)bh * S_ + sr) * D_ + d);
        ushort4 o; o.x = f2b(v.x); o.y = f2b(v.y); o.z = f2b(v.z); o.w = f2b(v.w);
        *(ushort4*)(Kp + ((size_t)bh * KROWS + r) * D_ + d) = o;
    } else {
        int b = bid - (QBLK + KBLK);
        int dt = b & 3; int kt = (b >> 2) & 31; int bh = b >> 7;
        int lk = tid >> 3, ld = (tid & 7) * 4;
        float4 v = *(const float4*)(V + ((size_t)bh * S_ + kt * 32 + lk) * D_ + dt * 32 + ld);
        ls[lk][ld + 0] = v.x; ls[lk][ld + 1] = v.y; ls[lk][ld + 2] = v.z; ls[lk][ld + 3] = v.w;
        __syncthreads();
        int lk2 = tid >> 3, lc = (tid & 7) * 4;
        ushort4 o;
        o.x = f2b(ls[lc + 0][lk2]); o.y = f2b(ls[lc + 1][lk2]);
        o.z = f2b(ls[lc + 2][lk2]); o.w = f2b(ls[lc + 3][lk2]);
        *(ushort4*)(Vt + ((size_t)bh * D_ + dt * 32 + lk2) * S_ + kt * 32 + lc) = o;
    }
}

// ---- main fused kernel ------------------------------------------------------
__global__ __launch_bounds__(256, 2) void conv_attn_mfma(
    const unsigned short* __restrict__ Qp,  // [24][1040][128] bf16
    const unsigned short* __restrict__ Kp,  // [24][1056][128] bf16
    const unsigned short* __restrict__ Vt,  // [24][128][1024] bf16
    const float* __restrict__ W,            // [12][6][11]
    float* __restrict__ O)                  // [24][1024][128] f32
{
    __shared__ __align__(16) unsigned short Qs[48][136];   // 13056 B, block-shared Q tile
    __shared__ __align__(16) union {
        float sc[NW][48][52];               // 39936 B, per-wave f32 score tiles
        float oacc[32][132];                // 16896 B, merge buffer
    } u;
    __shared__ float m_all[NW][32], l_all[NW][32], ms_s[32], inv_s[32];

    const int tid = threadIdx.x;
    const int wv = tid >> 6;
    const int ln = tid & 63;
    const int l15 = ln & 15;
    const int qd = ln >> 4;

    const int bid = blockIdx.x;
    const int bh = bid % (B_ * H_);
    const int qt = (S_ / TQ - 1) - bid / (B_ * H_);   // heavy tiles first
    const int h = bh % H_;
    const int q0 = qt * TQ;

    const unsigned short* Qb = Qp + (size_t)bh * QROWS * D_;
    const unsigned short* Kb = Kp + (size_t)bh * KROWS * D_;
    const unsigned short* Vb = Vt + (size_t)bh * D_ * S_;
    const float* Wh = W + h * 66;

    // stage Q tile (rows q0-16 .. q0+31 -> padded rows q0 .. q0+47) into LDS
    for (int idx = tid; idx < 48 * 16; idx += 256) {
        int r = idx >> 4, c8 = (idx & 15) * 8;
        *(short8*)&Qs[r][c8] = *(const short8*)(Qb + (size_t)(q0 + r) * D_ + c8);
    }
    __syncthreads();

    floatx4 acc[2][8];
    #pragma unroll
    for (int mt = 0; mt < 2; ++mt)
        #pragma unroll
        for (int nt = 0; nt < 8; ++nt)
            acc[mt][nt] = (floatx4){0.f, 0.f, 0.f, 0.f};
    float m_run[2] = {-INFINITY, -INFINITY};
    float l_run[2] = {0.f, 0.f};

    const int nkt = qt + 1;
    for (int kt = wv; kt < nkt; kt += NW) {
        const int k0 = kt * TK;

        // ---- scores: 48x48 tile via MFMA, masked, f32 -> LDS ---------------
        {
            short8 qf[3][4];
            #pragma unroll
            for (int mt = 0; mt < 3; ++mt)
                #pragma unroll
                for (int kc = 0; kc < 4; ++kc)
                    qf[mt][kc] = *(const short8*)&Qs[mt * 16 + l15][kc * 32 + qd * 8];
            #pragma unroll
            for (int nt = 0; nt < 3; ++nt) {
                const unsigned short* krow = Kb + (size_t)(k0 + 8 + nt * 16 + l15) * D_;
                short8 kf[4];
                #pragma unroll
                for (int kc = 0; kc < 4; ++kc)
                    kf[kc] = *(const short8*)(krow + kc * 32 + qd * 8);
                #pragma unroll
                for (int mt = 0; mt < 3; ++mt) {
                    floatx4 s = {0.f, 0.f, 0.f, 0.f};
                    #pragma unroll
                    for (int kc = 0; kc < 4; ++kc)
                        s = __builtin_amdgcn_mfma_f32_16x16x32_bf16(qf[mt][kc], kf[kc], s, 0, 0, 0);
                    const int qrow = q0 - 16 + mt * 16 + qd * 4;
                    const int kcol = k0 - 8 + nt * 16 + l15;
                    #pragma unroll
                    for (int reg = 0; reg < 4; ++reg)
                        u.sc[wv][mt * 16 + qd * 4 + reg][nt * 16 + l15] =
                            (kcol <= qrow + reg) ? s[reg] : 0.f;
                }
            }
        }

        // ---- 6x11 conv on VALU, f32 scores from LDS ------------------------
        float pl[2][8];
        #pragma unroll
        for (int mt2 = 0; mt2 < 2; ++mt2)
            #pragma unroll
            for (int jj = 0; jj < 8; ++jj) pl[mt2][jj] = 0.f;
        #pragma unroll
        for (int mt2 = 0; mt2 < 2; ++mt2) {
            #pragma unroll
            for (int i = 0; i < 6; ++i) {
                const float* rp = &u.sc[wv][l15 + 11 + 16 * mt2 + i][qd * 8];
                float4 a0 = ((const float4*)rp)[0];
                float4 a1 = ((const float4*)rp)[1];
                float4 a2 = ((const float4*)rp)[2];
                float4 a3 = ((const float4*)rp)[3];
                float4 a4 = ((const float4*)rp)[4];
                float2 a5 = *(const float2*)(rp + 20);
                float win[22] = {a0.x, a0.y, a0.z, a0.w, a1.x, a1.y, a1.z, a1.w,
                                 a2.x, a2.y, a2.z, a2.w, a3.x, a3.y, a3.z, a3.w,
                                 a4.x, a4.y, a4.z, a4.w, a5.x, a5.y};
                #pragma unroll
                for (int j = 0; j < 11; ++j) {
                    const float w = Wh[i * 11 + j];   // uniform -> SGPR
                    #pragma unroll
                    for (int jj = 0; jj < 8; ++jj)
                        pl[mt2][jj] = fmaf(w, win[3 + j + jj], pl[mt2][jj]);
                }
            }
        }

        // ---- online softmax (per wave, rows split across quads) ------------
        float al[2];
        short8 pfrag[2];
        #pragma unroll
        for (int mt2 = 0; mt2 < 2; ++mt2) {
            const int qrow = q0 + l15 + 16 * mt2;
            float lg[8];
            float mx = -1e30f;
            #pragma unroll
            for (int jj = 0; jj < 8; ++jj) {
                const int kcol = k0 + qd * 8 + jj;
                lg[jj] = (kcol <= qrow) ? pl[mt2][jj] * SCALE : -1e30f;
                mx = fmaxf(mx, lg[jj]);
            }
            mx = fmaxf(mx, __shfl_xor(mx, 16));
            mx = fmaxf(mx, __shfl_xor(mx, 32));
            const float nm = fmaxf(m_run[mt2], mx);
            al[mt2] = __expf(m_run[mt2] - nm);
            float sum = 0.f;
            short8 pb;
            #pragma unroll
            for (int jj = 0; jj < 8; ++jj) {
                float p = __expf(lg[jj] - nm);
                sum += p;
                pb[jj] = (short)f2b(p);
            }
            sum += __shfl_xor(sum, 16);
            sum += __shfl_xor(sum, 32);
            l_run[mt2] = l_run[mt2] * al[mt2] + sum;
            m_run[mt2] = nm;
            pfrag[mt2] = pb;
        }

        // rescale accumulator
        #pragma unroll
        for (int mt = 0; mt < 2; ++mt) {
            #pragma unroll
            for (int reg = 0; reg < 4; ++reg) {
                const float af = __shfl(al[mt], qd * 4 + reg, 64);
                #pragma unroll
                for (int nt = 0; nt < 8; ++nt)
                    acc[mt][nt][reg] *= af;
            }
        }

        // ---- P @ V via MFMA (V fragments loaded late: short live range) ----
        {
            short8 vf[8];
            #pragma unroll
            for (int nt = 0; nt < 8; ++nt)
                vf[nt] = *(const short8*)(Vb + (size_t)(nt * 16 + l15) * S_ + k0 + qd * 8);
            #pragma unroll
            for (int nt = 0; nt < 8; ++nt)
                #pragma unroll
                for (int mt = 0; mt < 2; ++mt)
                    acc[mt][nt] = __builtin_amdgcn_mfma_f32_16x16x32_bf16(pfrag[mt], vf[nt], acc[mt][nt], 0, 0, 0);
        }
    }

    // ---- merge the 4 waves' partials ---------------------------------------
    if (qd == 0) {
        m_all[wv][l15] = m_run[0]; m_all[wv][l15 + 16] = m_run[1];
        l_all[wv][l15] = l_run[0]; l_all[wv][l15 + 16] = l_run[1];
    }
    __syncthreads();
    if (tid < 32) {
        float ms = -INFINITY;
        #pragma unroll
        for (int w = 0; w < NW; ++w) ms = fmaxf(ms, m_all[w][tid]);
        float ls = 0.f;
        #pragma unroll
        for (int w = 0; w < NW; ++w) ls += __expf(m_all[w][tid] - ms) * l_all[w][tid];
        ms_s[tid] = ms;
        inv_s[tid] = 1.f / ls;
    }
    __syncthreads();
    for (int w = 0; w < NW; ++w) {
        if (wv == w) {
            #pragma unroll
            for (int mt = 0; mt < 2; ++mt) {
                #pragma unroll
                for (int reg = 0; reg < 4; ++reg) {
                    const int row = mt * 16 + qd * 4 + reg;
                    const float f = __expf(m_all[wv][row] - ms_s[row]);
                    #pragma unroll
                    for (int nt = 0; nt < 8; ++nt) {
                        const float val = acc[mt][nt][reg] * f;
                        if (w == 0) u.oacc[row][nt * 16 + l15] = val;
                        else        u.oacc[row][nt * 16 + l15] += val;
                    }
                }
            }
        }
        __syncthreads();
    }

    // ---- normalize + store --------------------------------------------------
    {
        const int r = tid >> 3;
        const int c0 = (tid & 7) * 16;
        const float inv = inv_s[r];
        float* orow = O + ((size_t)bh * S_ + q0 + r) * D_ + c0;
        #pragma unroll
        for (int g = 0; g < 4; ++g) {
            float4 o;
            o.x = u.oacc[r][c0 + g * 4 + 0] * inv;
            o.y = u.oacc[r][c0 + g * 4 + 1] * inv;
            o.z = u.oacc[r][c0 + g * 4 + 2] * inv;
            o.w = u.oacc[r][c0 + g * 4 + 3] * inv;
            *(float4*)(orow + g * 4) = o;
        }
    }
}

extern "C" void kernel_launch(void* const* d_in, const int* in_sizes, int n_in,
                              void* d_out, int out_size, void* d_ws, size_t ws_size,
                              hipStream_t stream) {
    const float* Q = (const float*)d_in[0];
    const float* K = (const float*)d_in[1];
    const float* V = (const float*)d_in[2];
    const float* W = (const float*)d_in[3];
    float* O = (float*)d_out;

    unsigned short* Qp = (unsigned short*)d_ws;                        // 6389760 B
    unsigned short* Kp = (unsigned short*)((char*)d_ws + 6389760);     // 6488064 B
    unsigned short* Vt = (unsigned short*)((char*)d_ws + 12877824);    // 6291456 B

    prep_kernel<<<dim3(QBLK + KBLK + VBLK), dim3(256), 0, stream>>>(Q, K, V, Qp, Kp, Vt);
    conv_attn_mfma<<<dim3(B_ * H_ * (S_ / TQ)), dim3(256), 0, stream>>>(Qp, Kp, Vt, W, O);
}